// Round 1
// baseline (222.268 us; speedup 1.0000x reference)
//
#include <hip/hip_runtime.h>

// Problem constants (from reference): x [B=8, H=224, W=224, D=8, C=8] fp32,
// out [8, 8, 8, 10] fp32. DC = D*C = 64 channels contiguous innermost.
#define BB 8
#define HH 224
#define WW 224
#define DCH 64
#define NS 10      // scales 1..10
#define SEG_OUT 55 // output columns owned per wave (64 lanes - 9 halo)
#define NSEG 5     // ceil(224 / 55)
#define STRIP 56   // output rows per h-strip
#define NSTRIP 4   // 4 * 56 = 224

__global__ void zero_kernel(float* out, int n) {
    int i = blockIdx.x * blockDim.x + threadIdx.x;
    if (i < n) out[i] = 0.0f;
}

__global__ void finalize_kernel(float* out, int n) {
    int i = blockIdx.x * blockDim.x + threadIdx.x;
    if (i < n) out[i] = fmaxf(out[i], 0.0f) + 1.0f;
}

// One wave = (b, 4-channel group, w-segment, h-strip).
// Block = 4 waves = 16 consecutive channels (one 64B line per (h,w)).
// Grid = 8 * 4 * 5 * 4 = 640 blocks of 256 threads.
__global__ __launch_bounds__(256, 2) void pool_kernel(const float* __restrict__ x,
                                                      float* __restrict__ out) {
    const int bid   = blockIdx.x;
    const int cgblk = bid & 3;                  // which 16-channel block
    const int ws    = (bid >> 2) % NSEG;        // w segment
    const int hs    = ((bid >> 2) / NSEG) % NSTRIP;
    const int b     = bid / (4 * NSEG * NSTRIP);

    const int wave = threadIdx.x >> 6;
    const int lane = threadIdx.x & 63;
    const int ch   = cgblk * 16 + wave * 4;     // 4 channels per lane (float4)
    const int col  = ws * SEG_OUT + lane;       // this lane's column
    const int row0 = hs * STRIP;
    const int rend = min(row0 + STRIP + (NS - 1), HH);

    // Per-scale column-ownership mask (0/1 float, used via fma; loads pad 0.0
    // so garbage stays finite and fma(g, 0, acc) is exact).
    float m[NS];
#pragma unroll
    for (int s = 1; s <= NS; ++s)
        m[s - 1] = (lane < SEG_OUT && col <= WW - s) ? 1.0f : 0.0f;

    float prev[NS - 1][4]; // previous pyramid row, scales 1..9
    float acc[NS][4];
#pragma unroll
    for (int s = 0; s < NS - 1; ++s)
#pragma unroll
        for (int c = 0; c < 4; ++c) prev[s][c] = 0.0f;
#pragma unroll
    for (int s = 0; s < NS; ++s)
#pragma unroll
        for (int c = 0; c < 4; ++c) acc[s][c] = 0.0f;

    const bool colok = (col < WW);
    const float* px = x + (((size_t)(b * HH + row0) * WW + col) * DCH + ch);
    const size_t rstride = (size_t)WW * DCH;

    float4 nxt = colok ? *(const float4*)px : make_float4(0.f, 0.f, 0.f, 0.f);

    for (int h = row0; h < rend; ++h) {
        float cp[4] = {nxt.x, nxt.y, nxt.z, nxt.w}; // cur row at scale s-1 (starts as x = scale 1)
        if (h + 1 < rend) { // prefetch next row (uniform branch)
            px += rstride;
            if (colok) nxt = *(const float4*)px;
        }
        if (h < row0 + STRIP) { // scale-1 accumulation (row h is output row h)
#pragma unroll
            for (int c = 0; c < 4; ++c) acc[0][c] = fmaf(cp[c], m[0], acc[0][c]);
        }
#pragma unroll
        for (int s = 2; s <= NS; ++s) {
            float vmax[4], vn[4];
#pragma unroll
            for (int c = 0; c < 4; ++c) vmax[c] = fmaxf(prev[s - 2][c], cp[c]); // vertical max
#pragma unroll
            for (int c = 0; c < 4; ++c) vn[c] = __shfl_down(vmax[c], 1);        // j+1 neighbor
#pragma unroll
            for (int c = 0; c < 4; ++c) prev[s - 2][c] = cp[c];                 // rotate
#pragma unroll
            for (int c = 0; c < 4; ++c) cp[c] = fmaxf(vmax[c], vn[c]);          // P_s row h-s+1
            const int r = h - s + 1;
            if (r >= row0 && r < row0 + STRIP) { // uniform row-ownership branch
#pragma unroll
                for (int c = 0; c < 4; ++c) acc[s - 1][c] = fmaf(cp[c], m[s - 1], acc[s - 1][c]);
            }
        }
    }

    // Wave butterfly reduction, then one lane atomics the 40 partials.
#pragma unroll
    for (int s = 0; s < NS; ++s) {
#pragma unroll
        for (int c = 0; c < 4; ++c) {
            float v = acc[s][c];
#pragma unroll
            for (int off = 32; off > 0; off >>= 1) v += __shfl_xor(v, off);
            if (lane == 0) atomicAdd(&out[((size_t)b * DCH + ch + c) * NS + s], v);
        }
    }
}

extern "C" void kernel_launch(void* const* d_in, const int* in_sizes, int n_in,
                              void* d_out, int out_size, void* d_ws, size_t ws_size,
                              hipStream_t stream) {
    const float* x = (const float*)d_in[0];
    float* out = (float*)d_out;
    const int nblk = (out_size + 255) / 256;
    zero_kernel<<<nblk, 256, 0, stream>>>(out, out_size);
    pool_kernel<<<BB * 4 * NSEG * NSTRIP, 256, 0, stream>>>(x, out);
    finalize_kernel<<<nblk, 256, 0, stream>>>(out, out_size);
}